// Round 1
// baseline (15938.202 us; speedup 1.0000x reference)
//
#include <hip/hip_runtime.h>
#include <cstddef>

#define D 512
#define D4 128
#define K 1024
#define NQ 8
#define BM 32
#define RSTR 36          // padded row stride (floats) for transposed residual
#define NROWS 96000

__device__ __forceinline__ float getc(float4 v, int j) {
    return j == 0 ? v.x : (j == 1 ? v.y : (j == 2 ? v.z : v.w));
}

// ---------------- K1: codebook squared norms -> d_ws ----------------
__global__ __launch_bounds__(256) void rvq_norms(const float* __restrict__ cb,
                                                 float* __restrict__ norms) {
    int gid  = blockIdx.x * 256 + threadIdx.x;
    int code = gid >> 6;                    // one wave per code, 8192 codes
    int lane = threadIdx.x & 63;
    const float4* cb4 = (const float4*)cb;
    float4 a = cb4[(size_t)code * D4 + lane * 2 + 0];
    float4 b = cb4[(size_t)code * D4 + lane * 2 + 1];
    float s = a.x*a.x + a.y*a.y + a.z*a.z + a.w*a.w
            + b.x*b.x + b.y*b.y + b.z*b.z + b.w*b.w;
    #pragma unroll
    for (int m = 1; m < 64; m <<= 1) s += __shfl_xor(s, m);
    if (lane == 0) norms[code] = s;
}

// ---------------- K2: fused residual VQ over all 8 quantizers ----------------
__global__ __launch_bounds__(256, 1) void rvq_main(const float* __restrict__ x,
        const float* __restrict__ cb, const float* __restrict__ norms,
        float* __restrict__ out_idx, float* __restrict__ out_q) {
    __shared__ float  res[D * RSTR];        // transposed residual [d][row], 73728 B
    __shared__ float4 ech[8 * 256];         // codebook chunk [8 d][256 granules], swizzled, 32 KB
    __shared__ float  smin[4][BM];
    __shared__ int    sidx[4][BM];
    __shared__ int    sfin[BM];

    const int tid  = threadIdx.x;
    const int lane = tid & 63;
    const int w    = tid >> 6;
    const int rg   = tid & 3;               // row group: rows rg*8 .. rg*8+7
    const int cgg  = tid >> 2;              // code group 0..63: codes cgg*16 .. +15
    const int R0   = blockIdx.x * BM;

    const float4* x4 = (const float4*)x;

    // load x tile into transposed residual
    #pragma unroll
    for (int i = 0; i < 16; ++i) {
        int lin4 = tid + 256 * i;
        int row  = lin4 >> 7;
        int d4   = lin4 & 127;
        float4 v = x4[(size_t)(R0 + row) * D4 + d4];
        res[(4*d4+0)*RSTR + row] = v.x;
        res[(4*d4+1)*RSTR + row] = v.y;
        res[(4*d4+2)*RSTR + row] = v.z;
        res[(4*d4+3)*RSTR + row] = v.w;
    }

    const int myB  = tid;                               // owned granule column 0..255
    const int swzB = myB ^ ((myB >> 3) & 7);
    const int sg0  = (4*cgg+0) ^ (((4*cgg+0) >> 3) & 7);
    const int sg1  = (4*cgg+1) ^ (((4*cgg+1) >> 3) & 7);
    const int sg2  = (4*cgg+2) ^ (((4*cgg+2) >> 3) & 7);
    const int sg3  = (4*cgg+3) ^ (((4*cgg+3) >> 3) & 7);

    #pragma unroll 1
    for (int q = 0; q < NQ; ++q) {
        const float4* cbq4 = (const float4*)(cb + (size_t)q * K * D);
        float acc[8][16];
        #pragma unroll
        for (int r = 0; r < 8; ++r)
            #pragma unroll
            for (int c = 0; c < 16; ++c) acc[r][c] = 0.f;

        float4 ld[16];                      // 4 codes x 64 B (one chunk-pair) prefetch
        #pragma unroll
        for (int c = 0; c < 4; ++c)
            #pragma unroll
            for (int h = 0; h < 4; ++h)
                ld[c*4+h] = cbq4[(size_t)(4*myB + c) * D4 + h];

        #pragma unroll 1
        for (int p = 0; p < 32; ++p) {      // 32 pairs x 16 d = 512
            #pragma unroll
            for (int half = 0; half < 2; ++half) {
                __syncthreads();            // previous chunk fully consumed
                // transpose-store regs -> swizzled LDS chunk [8][1024]
                #pragma unroll
                for (int h = 0; h < 2; ++h)
                    #pragma unroll
                    for (int j = 0; j < 4; ++j)
                        ech[(4*h+j)*256 + swzB] = make_float4(
                            getc(ld[0  + 2*half + h], j),
                            getc(ld[4  + 2*half + h], j),
                            getc(ld[8  + 2*half + h], j),
                            getc(ld[12 + 2*half + h], j));
                __syncthreads();            // chunk visible
                if (half == 1 && p != 31) { // prefetch next pair under GEMM
                    #pragma unroll
                    for (int c = 0; c < 4; ++c)
                        #pragma unroll
                        for (int h = 0; h < 4; ++h)
                            ld[c*4+h] = cbq4[(size_t)(4*myB + c) * D4 + (p+1)*4 + h];
                }
                const int dbase = p*16 + half*8;
                #pragma unroll
                for (int d = 0; d < 8; ++d) {
                    const float* rp = &res[(dbase + d)*RSTR + rg*8];
                    float4 ra = *(const float4*)rp;
                    float4 rb = *(const float4*)(rp + 4);
                    float4 e0 = ech[d*256 + sg0];
                    float4 e1 = ech[d*256 + sg1];
                    float4 e2 = ech[d*256 + sg2];
                    float4 e3 = ech[d*256 + sg3];
                    float rr[8]  = {ra.x,ra.y,ra.z,ra.w,rb.x,rb.y,rb.z,rb.w};
                    float ee[16] = {e0.x,e0.y,e0.z,e0.w,e1.x,e1.y,e1.z,e1.w,
                                    e2.x,e2.y,e2.z,e2.w,e3.x,e3.y,e3.z,e3.w};
                    #pragma unroll
                    for (int r = 0; r < 8; ++r)
                        #pragma unroll
                        for (int c = 0; c < 16; ++c)
                            acc[r][c] = fmaf(rr[r], ee[c], acc[r][c]);
                }
            }
        }

        // scores = |e|^2 - 2 r.e ; argmin with first-min tie-break
        #pragma unroll
        for (int r = 0; r < 8; ++r) {
            float bs = 3.4e38f; int bi = 0;
            #pragma unroll
            for (int c = 0; c < 16; ++c) {
                int code = cgg*16 + c;
                float s = fmaf(-2.f, acc[r][c], norms[q*K + code]);
                if (s < bs) { bs = s; bi = code; }
            }
            #pragma unroll
            for (int m = 4; m <= 32; m <<= 1) {   // reduce over 16 code-groups in wave
                float os = __shfl_xor(bs, m);
                int   oi = __shfl_xor(bi, m);
                if (os < bs || (os == bs && oi < bi)) { bs = os; bi = oi; }
            }
            if ((lane >> 2) == 0) { smin[w][rg*8+r] = bs; sidx[w][rg*8+r] = bi; }
        }
        __syncthreads();
        if (tid < BM) {
            float bs = smin[0][tid]; int bi = sidx[0][tid];
            #pragma unroll
            for (int ww = 1; ww < 4; ++ww) {
                float os = smin[ww][tid]; int oi = sidx[ww][tid];
                if (os < bs || (os == bs && oi < bi)) { bs = os; bi = oi; }
            }
            sfin[tid] = bi;
            out_idx[(size_t)q * NROWS + R0 + tid] = (float)bi;
        }
        __syncthreads();

        // residual -= chosen code (each LDS element owned by exactly one thread)
        {
            const float* cbq = cb + (size_t)q * K * D;
            int row = tid & 31;
            int dbs = tid >> 5;
            const float* eve = cbq + (size_t)sfin[row] * D + dbs;
            #pragma unroll 8
            for (int i = 0; i < 64; ++i)
                res[(dbs + 8*i)*RSTR + row] -= eve[8*i];
        }
        // next q: the two barriers before the first GEMM read protect res/ech
    }

    __syncthreads();
    // quantized = x - final residual
    float4* oq4 = (float4*)out_q;
    #pragma unroll
    for (int i = 0; i < 16; ++i) {
        int lin4 = tid + 256 * i;
        int row  = lin4 >> 7;
        int d4   = lin4 & 127;
        float4 xv = x4[(size_t)(R0 + row) * D4 + d4];
        float4 rv;
        rv.x = res[(4*d4+0)*RSTR + row];
        rv.y = res[(4*d4+1)*RSTR + row];
        rv.z = res[(4*d4+2)*RSTR + row];
        rv.w = res[(4*d4+3)*RSTR + row];
        oq4[(size_t)(R0 + row) * D4 + d4] =
            make_float4(xv.x - rv.x, xv.y - rv.y, xv.z - rv.z, xv.w - rv.w);
    }
}

extern "C" void kernel_launch(void* const* d_in, const int* in_sizes, int n_in,
                              void* d_out, int out_size, void* d_ws, size_t ws_size,
                              hipStream_t stream) {
    const float* x  = (const float*)d_in[0];   // [16,6000,512]
    const float* cb = (const float*)d_in[1];   // [8,1024,512]
    float* norms    = (float*)d_ws;            // 8192 floats
    float* out_idx  = (float*)d_out;                    // [8,16,6000] as float
    float* out_q    = (float*)d_out + (size_t)NQ*NROWS; // [16,6000,512]

    rvq_norms<<<(NQ * K) / 4, 256, 0, stream>>>(cb, norms);
    rvq_main<<<NROWS / BM, 256, 0, stream>>>(x, cb, norms, out_idx, out_q);
}